// Round 2
// baseline (459.818 us; speedup 1.0000x reference)
//
#include <hip/hip_runtime.h>

// Problem constants
#define Bn 256
#define Vn 512
#define Fn 256
// O = 2 hard-coded throughout.

// Workspace layout (bytes):
//   packed adjacency bits: [Bn*Vn][8] uint64  at 0        (8 MB)
//   dinv:                  [Bn*Vn] float      at 8388608   (512 KB)
//   Y = X@W:               [Bn*Vn] float2     at 8912896   (1 MB)
#define WS_PACKED_OFF 0
#define WS_DINV_OFF   8388608
#define WS_Y_OFF      8912896

// Fused kernel 1: one wave per row r = b*Vn+v.
//  (a) reads graphs row as 2x int4/lane (1 KiB per load instr), ballots into
//      8 packed u64 words (interleaved layout: word (c*4+j), bit k  <->
//      column 256*c + 4*k + j), forces the self-loop bit, popcounts -> dinv.
//  (b) reads features row as float4/lane, dots with W[:,0..1], butterfly
//      reduce -> Y[row].
__global__ __launch_bounds__(256) void fused_stage_kernel(
    const int4* __restrict__ G4,
    const float* __restrict__ X,
    const float* __restrict__ W,
    unsigned long long* __restrict__ P,
    float* __restrict__ dinv,
    float2* __restrict__ Y) {
  int gid  = blockIdx.x * 256 + threadIdx.x;
  int row  = gid >> 6;          // wave-uniform
  int lane = gid & 63;
  int v    = row & (Vn - 1);

  // ---- issue all global loads up front (latency overlap) ----
  const int4* gr = G4 + (size_t)row * (Vn / 4);
  int4 g0 = gr[lane];           // columns 4*lane + j          (chunk 0)
  int4 g1 = gr[lane + 64];      // columns 256 + 4*lane + j    (chunk 1)

  const float4* xr = (const float4*)(X + (size_t)row * Fn);
  float4 xf = xr[lane];
  const float4* wr = (const float4*)W;
  float4 w0 = wr[lane * 2];      // {W[4L][0],W[4L][1],W[4L+1][0],W[4L+1][1]}
  float4 w1 = wr[lane * 2 + 1];  // {W[4L+2][0],W[4L+2][1],W[4L+3][0],W[4L+3][1]}

  // ---- pack adjacency ----
  unsigned long long m[8];
  m[0] = __ballot(g0.x != 0);
  m[1] = __ballot(g0.y != 0);
  m[2] = __ballot(g0.z != 0);
  m[3] = __ballot(g0.w != 0);
  m[4] = __ballot(g1.x != 0);
  m[5] = __ballot(g1.y != 0);
  m[6] = __ballot(g1.z != 0);
  m[7] = __ballot(g1.w != 0);

  // self-loop bit: column v -> word ((v>>8)*4 + (v&3)), bit ((v>>2)&63)
  int widx = ((v >> 8) << 2) | (v & 3);        // wave-uniform
  unsigned long long db = 1ull << ((v >> 2) & 63);
  #pragma unroll
  for (int i = 0; i < 8; ++i) m[i] |= (widx == i) ? db : 0ull;

  int deg = __popcll(m[0]) + __popcll(m[1]) + __popcll(m[2]) + __popcll(m[3]) +
            __popcll(m[4]) + __popcll(m[5]) + __popcll(m[6]) + __popcll(m[7]);

  // ---- X @ W ----
  float s0 = xf.x * w0.x + xf.y * w0.z + xf.z * w1.x + xf.w * w1.z;
  float s1 = xf.x * w0.y + xf.y * w0.w + xf.z * w1.y + xf.w * w1.w;
  #pragma unroll
  for (int off = 32; off; off >>= 1) {
    s0 += __shfl_xor(s0, off);
    s1 += __shfl_xor(s1, off);
  }

  // ---- stores ----
  unsigned long long sel = m[0];
  #pragma unroll
  for (int i = 1; i < 8; ++i) sel = (lane == i) ? m[i] : sel;
  if (lane < 8) P[(size_t)row * 8 + lane] = sel;
  if (lane == 0) {
    dinv[row] = rsqrtf((float)deg);
    Y[row] = make_float2(s0, s1);
  }
}

// Kernel 2: per-batch aggregation + bias + relu + head dot + sigmoid.
// One block per b. LDS holds Y[b,w,:]*dinv[b,w]. Each thread owns rows
// v and v+256 (shares the broadcast LDS read between them).
// Bit layout matches fused_stage_kernel: word (c*4+j), bit k <-> col 256c+4k+j.
__global__ __launch_bounds__(256) void agg_head_kernel(
    const unsigned long long* __restrict__ P,
    const float* __restrict__ dinv,
    const float2* __restrict__ Y,
    const float* __restrict__ lw,
    const float* __restrict__ lb,
    const float* __restrict__ cb,
    float* __restrict__ out) {
  __shared__ float2 ylds[Vn];
  __shared__ float wsum[4];

  int b = blockIdx.x;
  int t = threadIdx.x;

  // Stage Y * dinv[w] (fold column normalization here)
  #pragma unroll
  for (int i = t; i < Vn; i += 256) {
    float  d = dinv[b * Vn + i];
    float2 y = Y[b * Vn + i];
    ylds[i] = make_float2(y.x * d, y.y * d);
  }
  __syncthreads();

  int v0 = t, v1 = t + 256;
  const unsigned long long* p0 = P + ((size_t)b * Vn + v0) * 8;
  const unsigned long long* p1 = P + ((size_t)b * Vn + v1) * 8;

  float a00 = 0.f, a01 = 0.f, a10 = 0.f, a11 = 0.f;
  #pragma unroll
  for (int c = 0; c < 2; ++c) {
    #pragma unroll
    for (int j = 0; j < 4; ++j) {
      unsigned long long m0 = p0[c * 4 + j];
      unsigned long long m1 = p1[c * 4 + j];
      const float2* base = ylds + c * 256 + j;
      #pragma unroll
      for (int k = 0; k < 64; ++k) {
        float2 y = base[k * 4];                 // wave-uniform broadcast read
        float s0 = (float)((m0 >> k) & 1ull);   // bfe + cvt
        float s1 = (float)((m1 >> k) & 1ull);
        a00 = fmaf(s0, y.x, a00);
        a01 = fmaf(s0, y.y, a01);
        a10 = fmaf(s1, y.x, a10);
        a11 = fmaf(s1, y.y, a11);
      }
    }
  }

  float d0 = dinv[b * Vn + v0];
  float d1 = dinv[b * Vn + v1];
  float cb0 = cb[0], cb1 = cb[1];
  const float2* lw2 = (const float2*)lw;
  float2 w0v = lw2[v0];
  float2 w1v = lw2[v1];

  float h00 = fmaxf(fmaf(d0, a00, cb0), 0.f);
  float h01 = fmaxf(fmaf(d0, a01, cb1), 0.f);
  float h10 = fmaxf(fmaf(d1, a10, cb0), 0.f);
  float h11 = fmaxf(fmaf(d1, a11, cb1), 0.f);
  float c = h00 * w0v.x + h01 * w0v.y + h10 * w1v.x + h11 * w1v.y;

  #pragma unroll
  for (int off = 32; off; off >>= 1) c += __shfl_xor(c, off);
  if ((t & 63) == 0) wsum[t >> 6] = c;
  __syncthreads();
  if (t == 0) {
    float logit = wsum[0] + wsum[1] + wsum[2] + wsum[3] + lb[0];
    out[b] = 1.0f / (1.0f + expf(-logit));
  }
}

extern "C" void kernel_launch(void* const* d_in, const int* in_sizes, int n_in,
                              void* d_out, int out_size, void* d_ws, size_t ws_size,
                              hipStream_t stream) {
  const float* features = (const float*)d_in[0];
  const int*   graphs   = (const int*)d_in[1];
  const float* conv_w   = (const float*)d_in[2];
  const float* conv_b   = (const float*)d_in[3];
  const float* lin_w    = (const float*)d_in[4];
  const float* lin_b    = (const float*)d_in[5];
  float* out = (float*)d_out;

  char* ws = (char*)d_ws;
  unsigned long long* P = (unsigned long long*)(ws + WS_PACKED_OFF);
  float*  dinv = (float*)(ws + WS_DINV_OFF);
  float2* Y    = (float2*)(ws + WS_Y_OFF);

  // Fused pack+deg+XW: 131072 rows, one wave each -> 32768 blocks of 256
  fused_stage_kernel<<<dim3(32768), dim3(256), 0, stream>>>(
      (const int4*)graphs, features, conv_w, P, dinv, Y);
  // One block per batch element
  agg_head_kernel<<<dim3(Bn), dim3(256), 0, stream>>>(P, dinv, Y, lin_w, lin_b, conv_b, out);
}